// Round 19
// baseline (133.241 us; speedup 1.0000x reference)
//
#include <hip/hip_runtime.h>
#include <math.h>

// flash-decode, GQA paged KV. R=4, B=16, Hq=32, Hk=8 (G=4), D=128, P=8192,
// PAGE=1, M=2048. Storage (r7): q/k/v FLOAT32; lens/bt int32; out f32.
//
// Round 19: page-sorted EQUAL-COUNT chunks. r18's page-range segments
// halved HBM traffic (FETCH 262->119 MB, L2 band sharing) but ranges are
// binomially imbalanced (count ~ Binomial(kvlen,1/8)) -> occupancy 26%.
// Now each (r,b)'s sorted list is cut into NR=16 chunks of exactly
// ceil(kvlen/16) tokens; uniform-random pages make equal-count chunks
// quantile-aligned (chunk s of every rb covers pages ~ quantile s/16)
// so band sharing survives while per-block work equalizes. s slowest in
// blockIdx. Proven r13 body (VGPR 76) unchanged.

typedef float f32x4 __attribute__((ext_vector_type(4)));

#define R_ 4
#define B_ 16
#define HQ_ 32
#define HK_ 8
#define G_ 4
#define D_ 128
#define P_ 8192
#define M_ 2048
#define HKD (HK_ * D_)
#define NR 16     // equal-count chunks per (r,b)
#define NBK 256   // sort buckets (page >> 5)
#define PROW 2112 // padded row capacity (2048 + 64 slack)
#define SC2 (0.08838834764831845f * 1.4426950408889634f)  // scale * log2(e)
#define MNEG (-1.0e30f)

__device__ __forceinline__ int clampP(int p) {
  return p < 0 ? 0 : (p >= P_ ? P_ - 1 : p);
}

// ---------- kernel 0: per-(r,b) counting sort + tail padding ----------
__global__ __launch_bounds__(256) void fd_compact(
    const int* __restrict__ lens, const int* __restrict__ bt,
    unsigned* __restrict__ ws_pages) {
  __shared__ int hist[NBK];
  __shared__ int cur[NBK];
  const int rb = blockIdx.x;
  const int tid = threadIdx.x;
  int kvlen = lens[rb];
  kvlen = kvlen < 1 ? 1 : (kvlen > M_ ? M_ : kvlen);
  const int* btrow = bt + rb * M_;

  for (int i = tid; i < NBK; i += 256) hist[i] = 0;
  __syncthreads();
  for (int t = tid; t < kvlen; t += 256)
    atomicAdd(&hist[clampP(btrow[t]) >> 5], 1);
  __syncthreads();
  if (tid == 0) {
    int pos = 0;
    for (int j = 0; j < NBK; ++j) {
      cur[j] = pos;
      pos += hist[j];
    }
  }
  __syncthreads();
  unsigned* prow = ws_pages + (size_t)rb * PROW;
  for (int t = tid; t < kvlen; t += 256) {
    const int p = clampP(btrow[t]);
    const int d = atomicAdd(&cur[p >> 5], 1);
    prow[d] = ((unsigned)p) << 12;  // byte offset of the page
  }
  __syncthreads();
  const unsigned last = prow[kvlen - 1];  // pad whole row slack: all
  for (int i = kvlen + tid; i < PROW; i += 256) prow[i] = last;  // reads safe
}

// ---------- kernel 1: block = (chunk s, r, b, hk); r13 body ----------
__global__ __launch_bounds__(256) void fd_partial(
    const float* __restrict__ q, const float* __restrict__ kc,
    const float* __restrict__ vc, const int* __restrict__ lens,
    const unsigned* __restrict__ ws_pages, float* __restrict__ ws_m,
    float* __restrict__ ws_l, float* __restrict__ ws_o) {
  const int bid = blockIdx.x;
  const int s = bid >> 9;  // chunk id, SLOWEST -> quantile bands in order
  const int rbh = bid & 511;
  const int hk = rbh & (HK_ - 1);
  const int rb = rbh >> 3;  // r*B + b
  const int b = rb & (B_ - 1);
  const int r = rb >> 4;
  const int rec = bid;

  const int lane = threadIdx.x & 63;
  const int w = threadIdx.x >> 6;   // wave -> 16-token strip per 64-window
  const int tg = lane >> 4;         // slot 0..3: 4 tokens each
  const int ds = (lane & 15) * 8;   // dim slice [ds, ds+8)
  const unsigned dsb = ds * 4u;

  int kvlen = lens[rb];
  kvlen = kvlen < 1 ? 1 : (kvlen > M_ ? M_ : kvlen);
  const int qn = (((kvlen + NR - 1) / NR) + 3) & ~3;  // 4-aligned chunk size
  const int start = s * qn;
  int nc = kvlen - start;
  if (nc <= 0) {  // inactive chunk (block-uniform)
    if (lane == 0) ws_m[rec * G_ + w] = MNEG;
    return;
  }
  if (nc > qn) nc = qn;

  // q fragments for all 4 heads, pre-scaled into log2 domain
  float qf[G_][8];
  {
    const float* qp = q + (size_t)(b * HQ_ + hk * G_) * D_ + ds;
#pragma unroll
    for (int h = 0; h < G_; ++h) {
      const f32x4* p = (const f32x4*)(qp + h * D_);
      f32x4 a = p[0], c = p[1];
#pragma unroll
      for (int j = 0; j < 4; ++j) {
        qf[h][j] = a[j] * SC2;
        qf[h][4 + j] = c[j] * SC2;
      }
    }
  }

  const unsigned* plist = ws_pages + (size_t)rb * PROW + start;
  const float* kb = kc + (size_t)r * P_ * HKD + (size_t)hk * D_;
  const float* vb = vc + (size_t)r * P_ * HKD + (size_t)hk * D_;

  float m[G_], l[G_], acc[G_][8];
#pragma unroll
  for (int h = 0; h < G_; ++h) {
    m[h] = MNEG;
    l[h] = 0.f;
#pragma unroll
    for (int j = 0; j < 8; ++j) acc[h][j] = 0.f;
  }

  const int nIt = (nc + 63) >> 6;
  const int sbase = w * 16 + tg * 4;  // 4-aligned; start is 4-aligned

  uint4 pgN = *(const uint4*)(plist + sbase);

#pragma unroll 1
  for (int i = 0; i < nIt; ++i) {
    const uint4 pg = pgN;
    if (i + 1 < nIt) pgN = *(const uint4*)(plist + sbase + (i + 1) * 64);
    const unsigned o0 = pg.x + dsb;
    const unsigned o1 = pg.y + dsb;
    const unsigned o2 = pg.z + dsb;
    const unsigned o3 = pg.w + dsb;

    float k0[8], k1[8], k2[8], k3[8], v0[8], v1[8], v2[8], v3[8];
    {
      const char* kcb = (const char*)kb;
      const char* vcb = (const char*)vb;
      const f32x4* p;
      p = (const f32x4*)(kcb + o0);
#pragma unroll
      for (int j = 0; j < 4; ++j) { k0[j] = p[0][j]; k0[4 + j] = p[1][j]; }
      p = (const f32x4*)(kcb + o1);
#pragma unroll
      for (int j = 0; j < 4; ++j) { k1[j] = p[0][j]; k1[4 + j] = p[1][j]; }
      p = (const f32x4*)(kcb + o2);
#pragma unroll
      for (int j = 0; j < 4; ++j) { k2[j] = p[0][j]; k2[4 + j] = p[1][j]; }
      p = (const f32x4*)(kcb + o3);
#pragma unroll
      for (int j = 0; j < 4; ++j) { k3[j] = p[0][j]; k3[4 + j] = p[1][j]; }
      p = (const f32x4*)(vcb + o0);
#pragma unroll
      for (int j = 0; j < 4; ++j) { v0[j] = p[0][j]; v0[4 + j] = p[1][j]; }
      p = (const f32x4*)(vcb + o1);
#pragma unroll
      for (int j = 0; j < 4; ++j) { v1[j] = p[0][j]; v1[4 + j] = p[1][j]; }
      p = (const f32x4*)(vcb + o2);
#pragma unroll
      for (int j = 0; j < 4; ++j) { v2[j] = p[0][j]; v2[4 + j] = p[1][j]; }
      p = (const f32x4*)(vcb + o3);
#pragma unroll
      for (int j = 0; j < 4; ++j) { v3[j] = p[0][j]; v3[4 + j] = p[1][j]; }
    }

    float d0[G_], d1[G_], d2[G_], d3[G_];
#pragma unroll
    for (int h = 0; h < G_; ++h) {
      float a0 = 0.f, a1 = 0.f, a2 = 0.f, a3 = 0.f;
#pragma unroll
      for (int j = 0; j < 8; ++j) {
        a0 += qf[h][j] * k0[j];
        a1 += qf[h][j] * k1[j];
        a2 += qf[h][j] * k2[j];
        a3 += qf[h][j] * k3[j];
      }
      d0[h] = a0; d1[h] = a1; d2[h] = a2; d3[h] = a3;
    }
#pragma unroll
    for (int msk = 1; msk <= 8; msk <<= 1) {
#pragma unroll
      for (int h = 0; h < G_; ++h) {
        d0[h] += __shfl_xor(d0[h], msk);
        d1[h] += __shfl_xor(d1[h], msk);
        d2[h] += __shfl_xor(d2[h], msk);
        d3[h] += __shfl_xor(d3[h], msk);
      }
    }

    const int tb = sbase + i * 64;  // index within the chunk
    const bool va0 = tb < nc;
    const bool va1 = tb + 1 < nc;
    const bool va2 = tb + 2 < nc;
    const bool va3 = tb + 3 < nc;
#pragma unroll
    for (int h = 0; h < G_; ++h) {
      const float s0 = va0 ? d0[h] : -INFINITY;
      const float s1 = va1 ? d1[h] : -INFINITY;
      const float s2 = va2 ? d2[h] : -INFINITY;
      const float s3 = va3 ? d3[h] : -INFINITY;
      const float mt = fmaxf(fmaxf(s0, s1), fmaxf(s2, s3));
      const float mn = fmaxf(m[h], mt);   // finite always (>= MNEG)
      const float sc = exp2f(m[h] - mn);  // branchless, no NaN
      const float p0 = exp2f(s0 - mn);    // -inf -> 0
      const float p1 = exp2f(s1 - mn);
      const float p2 = exp2f(s2 - mn);
      const float p3 = exp2f(s3 - mn);
      m[h] = mn;
      l[h] = l[h] * sc + (p0 + p1) + (p2 + p3);
#pragma unroll
      for (int j = 0; j < 8; ++j)
        acc[h][j] = acc[h][j] * sc + p0 * v0[j] + p1 * v1[j] + p2 * v2[j] +
                    p3 * v3[j];
    }
  }

  // merge the 4 token slots (xor 16, 32), per head — branchless
#pragma unroll
  for (int h = 0; h < G_; ++h) {
#pragma unroll
    for (int off = 16; off <= 32; off <<= 1) {
      const float mo = __shfl_xor(m[h], off);
      const float lo = __shfl_xor(l[h], off);
      float ao[8];
#pragma unroll
      for (int j = 0; j < 8; ++j) ao[j] = __shfl_xor(acc[h][j], off);
      const float mn = fmaxf(m[h], mo);
      const float se = exp2f(m[h] - mn);
      const float so_ = exp2f(mo - mn);
      l[h] = l[h] * se + lo * so_;
#pragma unroll
      for (int j = 0; j < 8; ++j) acc[h][j] = acc[h][j] * se + ao[j] * so_;
      m[h] = mn;
    }
  }

  // cross-wave merge via LDS; wave w finalizes head g = w
  __shared__ float sm[4][G_], sl[4][G_], so[4][G_][D_ + 4];
  if (lane < 16) {
#pragma unroll
    for (int h = 0; h < G_; ++h) {
#pragma unroll
      for (int j = 0; j < 8; ++j) so[w][h][ds + j] = acc[h][j];
    }
    if (lane == 0) {
#pragma unroll
      for (int h = 0; h < G_; ++h) {
        sm[w][h] = m[h];
        sl[w][h] = l[h];
      }
    }
  }
  __syncthreads();

  const int g = w;
  const float mw0 = sm[0][g], mw1 = sm[1][g], mw2 = sm[2][g], mw3 = sm[3][g];
  const float mf = fmaxf(fmaxf(mw0, mw1), fmaxf(mw2, mw3));
  const float wt0 = exp2f(mw0 - mf);
  const float wt1 = exp2f(mw1 - mf);
  const float wt2 = exp2f(mw2 - mf);
  const float wt3 = exp2f(mw3 - mf);
  const float lf =
      wt0 * sl[0][g] + wt1 * sl[1][g] + wt2 * sl[2][g] + wt3 * sl[3][g];
  const float of0 = wt0 * so[0][g][lane] + wt1 * so[1][g][lane] +
                    wt2 * so[2][g][lane] + wt3 * so[3][g][lane];
  const float of1 = wt0 * so[0][g][lane + 64] + wt1 * so[1][g][lane + 64] +
                    wt2 * so[2][g][lane + 64] + wt3 * so[3][g][lane + 64];
  ws_o[((size_t)rec * G_ + g) * D_ + lane] = of0;
  ws_o[((size_t)rec * G_ + g) * D_ + lane + 64] = of1;
  if (lane == 0) {
    ws_m[rec * G_ + g] = mf;  // log2-domain
    ws_l[rec * G_ + g] = lf;
  }
}

// ---------- kernel 2: LSE-weighted combine over R_*NR records ----------
__global__ __launch_bounds__(128) void fd_reduce(
    const float* __restrict__ ws_m, const float* __restrict__ ws_l,
    const float* __restrict__ ws_o, float* __restrict__ out) {
  const int row = blockIdx.x;  // (b*HK + hk)*G + g
  const int g = row % G_;
  const int hk = (row / G_) % HK_;
  const int b = row / (G_ * HK_);
  const int d = threadIdx.x;

  float mf = MNEG;
  for (int r = 0; r < R_; ++r)
    for (int s = 0; s < NR; ++s) {
      const int rec = s * 512 + (r * B_ + b) * HK_ + hk;
      mf = fmaxf(mf, ws_m[rec * G_ + g]);
    }
  float of = 0.f, lf = 0.f;
  for (int r = 0; r < R_; ++r)
    for (int s = 0; s < NR; ++s) {
      const int rec = s * 512 + (r * B_ + b) * HK_ + hk;
      const float wt = exp2f(ws_m[rec * G_ + g] - mf);  // empty -> 0
      of += wt * ws_o[((size_t)rec * G_ + g) * D_ + d];
      lf += wt * ws_l[rec * G_ + g];
    }
  out[(size_t)(b * HQ_ + hk * G_ + g) * D_ + d] = of / lf;
}

// ---------------- fallback: monolithic (tiny workspace) ----------------
__device__ __forceinline__ void load8u(const float* __restrict__ ubase,
                                       unsigned boff, float o[8]) {
  const f32x4* p = (const f32x4*)((const char*)ubase + boff);
  f32x4 a = p[0];
  f32x4 b = p[1];
#pragma unroll
  for (int j = 0; j < 4; ++j) { o[j] = a[j]; o[4 + j] = b[j]; }
}

__global__ __launch_bounds__(256) void fd_mono(
    const float* __restrict__ q, const float* __restrict__ kc,
    const float* __restrict__ vc, const int* __restrict__ lens,
    const int* __restrict__ bt, float* __restrict__ out) {
  const int hk = blockIdx.x % HK_;
  const int b = blockIdx.x / HK_;
  const int lane = threadIdx.x & 63;
  const int g = threadIdx.x >> 6;
  const int tg = lane >> 4;
  const int ds = (lane & 15) * 8;
  const unsigned dsb = ds * 4u;

  float qf[8];
  load8u(q + (size_t)(b * HQ_ + hk * G_ + g) * D_ + ds, 0u, qf);
#pragma unroll
  for (int j = 0; j < 8; ++j) qf[j] *= SC2;

  float m = MNEG, l = 0.f, acc[8];
#pragma unroll
  for (int j = 0; j < 8; ++j) acc[j] = 0.f;

  for (int r = 0; r < R_; ++r) {
    int kvlen = lens[r * B_ + b];
    if (kvlen < 0) kvlen = 0;
    if (kvlen > M_) kvlen = M_;
    const int* btrow = bt + (r * B_ + b) * M_;
    const float* kb = kc + (size_t)r * P_ * HKD + (size_t)hk * D_;
    const float* vb = vc + (size_t)r * P_ * HKD + (size_t)hk * D_;

#pragma unroll 1
    for (int t = 0; t < kvlen; t += 4) {
      const int ta = t + tg;
      const bool va = ta < kvlen;
      const unsigned oa = ((unsigned)clampP(btrow[va ? ta : 0]) << 12) + dsb;
      float ka[8], wa[8];
      load8u(kb, oa, ka);
      load8u(vb, oa, wa);

      float da = 0.f;
#pragma unroll
      for (int j = 0; j < 8; ++j) da += qf[j] * ka[j];
#pragma unroll
      for (int msk = 1; msk <= 8; msk <<= 1) da += __shfl_xor(da, msk);

      const float sa = va ? da : -INFINITY;
      const float mn = fmaxf(m, sa);
      const float sc = exp2f(m - mn);
      const float pa = exp2f(sa - mn);
      m = mn;
      l = l * sc + pa;
#pragma unroll
      for (int j = 0; j < 8; ++j) acc[j] = acc[j] * sc + pa * wa[j];
    }
  }

#pragma unroll
  for (int off = 16; off <= 32; off <<= 1) {
    const float mo = __shfl_xor(m, off);
    const float lo = __shfl_xor(l, off);
    float ao[8];
#pragma unroll
    for (int j = 0; j < 8; ++j) ao[j] = __shfl_xor(acc[j], off);
    const float mn = fmaxf(m, mo);
    const float se = exp2f(m - mn);
    const float so_ = exp2f(mo - mn);
    l = l * se + lo * so_;
#pragma unroll
    for (int j = 0; j < 8; ++j) acc[j] = acc[j] * se + ao[j] * so_;
    m = mn;
  }

  if (lane < 16) {
    float inv = (l > 0.f) ? 1.0f / l : 0.f;
#pragma unroll
    for (int j = 0; j < 8; ++j)
      out[(size_t)(b * HQ_ + hk * G_ + g) * D_ + ds + j] = acc[j] * inv;
  }
}

extern "C" void kernel_launch(void* const* d_in, const int* in_sizes, int n_in,
                              void* d_out, int out_size, void* d_ws,
                              size_t ws_size, hipStream_t stream) {
  const float* q = (const float*)d_in[0];
  const float* kc = (const float*)d_in[1];
  const float* vc = (const float*)d_in[2];
  const int* lens = (const int*)d_in[3];
  const int* bt = (const int*)d_in[4];
  float* out = (float*)d_out;

  const int nrec = NR * R_ * B_ * HK_;  // 8192 records
  const size_t sz_pages = (size_t)R_ * B_ * PROW * 4;  // 540 KB
  const size_t sz_ml = (size_t)nrec * G_ * 4;          // 128 KB each
  const size_t sz_o = (size_t)nrec * G_ * D_ * 4;      // 16 MB
  const size_t need = sz_pages + 2 * sz_ml + sz_o;

  if (need <= ws_size) {
    char* p = (char*)d_ws;
    unsigned* ws_pages = (unsigned*)p;  p += sz_pages;
    float* ws_m = (float*)p;            p += sz_ml;
    float* ws_l = (float*)p;            p += sz_ml;
    float* ws_o = (float*)p;
    fd_compact<<<R_ * B_, 256, 0, stream>>>(lens, bt, ws_pages);
    fd_partial<<<nrec, 256, 0, stream>>>(q, kc, vc, lens, ws_pages, ws_m,
                                         ws_l, ws_o);
    fd_reduce<<<B_ * HK_ * G_, 128, 0, stream>>>(ws_m, ws_l, ws_o, out);
  } else {
    fd_mono<<<B_ * HK_, 256, 0, stream>>>(q, kc, vc, lens, bt, out);
  }
}

// Round 20
// 132.301 us; speedup vs baseline: 1.0071x; 1.0071x over previous
//
#include <hip/hip_runtime.h>
#include <math.h>

// flash-decode, GQA paged KV. R=4, B=16, Hq=32, Hk=8 (G=4), D=128, P=8192,
// PAGE=1, M=2048. Storage (r7): q/k/v FLOAT32; lens/bt int32; out f32.
//
// Round 20 = r17's async global_load_lds pipeline (depth-3, counted
// vmcnt(8), VGPR~68, 1.9 TB/s issue rate measured) x r18/r19's page-sorted
// traversal (FETCH 262->119 MB via cross-b L2 dedup). NR=8 equal-count
// chunks (<=256 tokens -> page list fits LDS), record id s-SLOWEST so
// resident blocks sweep one quantile band, and the 2 waves of a block are
// adjacent hk of the same (s,r,b) -> same pages, mutually L2-warm.

typedef float f32x4 __attribute__((ext_vector_type(4)));

#define R_ 4
#define B_ 16
#define HQ_ 32
#define HK_ 8
#define G_ 4
#define D_ 128
#define P_ 8192
#define M_ 2048
#define HKD (HK_ * D_)
#define NR 8      // equal-count chunks per (r,b)
#define NBK 256   // sort buckets (page >> 5)
#define PROW 2112 // padded row capacity
#define T_ 4      // tokens per tile
#define DP 3      // pipeline depth
#define WV 2      // waves per block
#define SC2 (0.08838834764831845f * 1.4426950408889634f)  // scale * log2(e)
#define MNEG (-1.0e30f)

__device__ __forceinline__ int clampP(int p) {
  return p < 0 ? 0 : (p >= P_ ? P_ - 1 : p);
}

// ---------- kernel 0: per-(r,b) counting sort + tail padding ----------
__global__ __launch_bounds__(256) void fd_compact(
    const int* __restrict__ lens, const int* __restrict__ bt,
    unsigned* __restrict__ ws_pages) {
  __shared__ int hist[NBK];
  __shared__ int cur[NBK];
  const int rb = blockIdx.x;
  const int tid = threadIdx.x;
  int kvlen = lens[rb];
  kvlen = kvlen < 1 ? 1 : (kvlen > M_ ? M_ : kvlen);
  const int* btrow = bt + rb * M_;

  for (int i = tid; i < NBK; i += 256) hist[i] = 0;
  __syncthreads();
  for (int t = tid; t < kvlen; t += 256)
    atomicAdd(&hist[clampP(btrow[t]) >> 5], 1);
  __syncthreads();
  if (tid == 0) {
    int pos = 0;
    for (int j = 0; j < NBK; ++j) {
      cur[j] = pos;
      pos += hist[j];
    }
  }
  __syncthreads();
  unsigned* prow = ws_pages + (size_t)rb * PROW;
  for (int t = tid; t < kvlen; t += 256) {
    const int p = clampP(btrow[t]);
    const int d = atomicAdd(&cur[p >> 5], 1);
    prow[d] = ((unsigned)p) << 12;  // byte offset of the page
  }
  __syncthreads();
  const unsigned last = prow[kvlen - 1];
  for (int i = kvlen + tid; i < PROW; i += 256) prow[i] = last;
}

// ---------- kernel 1: one wave per (chunk s, r, b, hk), async ----------
__global__ __launch_bounds__(WV * 64) void fd_partial(
    const float* __restrict__ q, const float* __restrict__ kc,
    const float* __restrict__ vc, const int* __restrict__ lens,
    const unsigned* __restrict__ ws_pages, float* __restrict__ ws_m,
    float* __restrict__ ws_l, float* __restrict__ ws_o) {
  __shared__ unsigned s_pg[WV][256];
  __shared__ float s_k[WV][DP][T_ * D_];
  __shared__ float s_v[WV][DP][T_ * D_];

  const int lane = threadIdx.x & 63;
  const int w = threadIdx.x >> 6;
  const int gw = blockIdx.x * WV + w;  // record id; s SLOWEST
  const int s = gw >> 9;
  const int rbh = gw & 511;
  const int hk = rbh & (HK_ - 1);
  const int rb = rbh >> 3;
  const int b = rb & (B_ - 1);
  const int r = rb >> 4;

  const int tg = lane >> 4;  // slot 0..3: one token of the tile
  const int dl = lane & 15;  // dim-chunk index

  int kvlen = lens[rb];
  kvlen = kvlen < 1 ? 1 : (kvlen > M_ ? M_ : kvlen);
  const int qn = (((kvlen + NR - 1) / NR) + 3) & ~3;  // <= 256, 4-aligned
  const int start = s * qn;
  int ct = kvlen - start;
  if (ct <= 0) {  // inactive chunk: sentinel + exit (no barriers)
    if (lane == 0) {
#pragma unroll
      for (int h = 0; h < G_; ++h) ws_m[gw * G_ + h] = MNEG;
    }
    return;
  }
  if (ct > qn) ct = qn;
  const int cm1 = ct - 1;
  const int nT = (ct + T_ - 1) >> 2;

  // q fragments: dims [dl*4,+4) and [64+dl*4,+4), log2-domain pre-scale
  float qf[G_][8];
  {
    const float* qp = q + ((size_t)b * HQ_ + hk * G_) * D_;
#pragma unroll
    for (int h = 0; h < G_; ++h) {
      f32x4 a = *(const f32x4*)(qp + h * D_ + dl * 4);
      f32x4 c = *(const f32x4*)(qp + h * D_ + 64 + dl * 4);
#pragma unroll
      for (int j = 0; j < 4; ++j) {
        qf[h][j] = a[j] * SC2;
        qf[h][4 + j] = c[j] * SC2;
      }
    }
  }

  // phase 0: sorted page byte-offsets for this chunk into LDS
  {
    const unsigned* plist = ws_pages + (size_t)rb * PROW + start;
#pragma unroll
    for (int t = 0; t < 256; t += 64) {
      const int idx = t + lane;
      const int tt = idx > cm1 ? cm1 : idx;
      s_pg[w][idx] = plist[tt];
    }
  }

  const char* kb = (const char*)kc + ((size_t)r * P_) * 4096 + hk * 512;
  const char* vb = (const char*)vc + ((size_t)r * P_) * 4096 + hk * 512;
  const unsigned* pgw = s_pg[w];
  const unsigned lo16 = ((unsigned)(lane & 31)) << 4;

  float m[G_], l[G_], acc[G_][8];
#pragma unroll
  for (int h = 0; h < G_; ++h) {
    m[h] = MNEG;
    l[h] = 0.f;
#pragma unroll
    for (int j = 0; j < 8; ++j) acc[h][j] = 0.f;
  }

  asm volatile("s_waitcnt vmcnt(0) lgkmcnt(0)" ::: "memory");

  // stage tile k into slot sl: exactly 4 global_load_lds (K,V x 2 pairs)
  auto stage = [&](int k, int sl) {
#pragma unroll
    for (int j = 0; j < 2; ++j) {
      int tau = T_ * k + 2 * j + (lane >> 5);
      tau = tau > cm1 ? cm1 : tau;
      const unsigned pgo = pgw[tau];
      __builtin_amdgcn_global_load_lds((const float*)(kb + pgo + lo16),
                                       &s_k[w][sl][j * 256], 16, 0, 0);
      __builtin_amdgcn_global_load_lds((const float*)(vb + pgo + lo16),
                                       &s_v[w][sl][j * 256], 16, 0, 0);
    }
  };

  stage(0, 0);
  stage(1, 1);
  stage(2, 2);

  int sl = 0;
  for (int i = 0; i < nT; ++i) {
    asm volatile("s_waitcnt vmcnt(8)" ::: "memory");
    __builtin_amdgcn_sched_barrier(0);

    const float* kp = &s_k[w][sl][tg * D_];
    const float* vp = &s_v[w][sl][tg * D_];
    float kr[8], vr[8];
    {
      f32x4 a = *(const f32x4*)(kp + dl * 4);
      f32x4 c = *(const f32x4*)(kp + 64 + dl * 4);
#pragma unroll
      for (int j = 0; j < 4; ++j) { kr[j] = a[j]; kr[4 + j] = c[j]; }
    }
    float d0 = 0.f, d1 = 0.f, d2 = 0.f, d3 = 0.f;
#pragma unroll
    for (int j = 0; j < 8; ++j) {
      d0 += qf[0][j] * kr[j];
      d1 += qf[1][j] * kr[j];
      d2 += qf[2][j] * kr[j];
      d3 += qf[3][j] * kr[j];
    }
#pragma unroll
    for (int msk = 1; msk <= 8; msk <<= 1) {
      d0 += __shfl_xor(d0, msk);
      d1 += __shfl_xor(d1, msk);
      d2 += __shfl_xor(d2, msk);
      d3 += __shfl_xor(d3, msk);
    }
    {
      f32x4 a = *(const f32x4*)(vp + dl * 4);
      f32x4 c = *(const f32x4*)(vp + 64 + dl * 4);
#pragma unroll
      for (int j = 0; j < 4; ++j) { vr[j] = a[j]; vr[4 + j] = c[j]; }
    }
    const bool valid = (T_ * i + tg) < ct;
    float sH[G_];
    sH[0] = valid ? d0 : -INFINITY;
    sH[1] = valid ? d1 : -INFINITY;
    sH[2] = valid ? d2 : -INFINITY;
    sH[3] = valid ? d3 : -INFINITY;
#pragma unroll
    for (int h = 0; h < G_; ++h) {
      if (sH[h] > m[h]) {  // deferred rescale (exact)
        const float rs = exp2f(m[h] - sH[h]);
        l[h] *= rs;
#pragma unroll
        for (int j = 0; j < 8; ++j) acc[h][j] *= rs;
        m[h] = sH[h];
      }
      const float p = exp2f(sH[h] - m[h]);  // invalid -> 0
      l[h] += p;
#pragma unroll
      for (int j = 0; j < 8; ++j) acc[h][j] += p * vr[j];
    }

    __builtin_amdgcn_sched_barrier(0);
    stage(i + DP, sl);
    sl = (sl == DP - 1) ? 0 : sl + 1;
  }
  asm volatile("s_waitcnt vmcnt(0)" ::: "memory");

  // merge the 4 token slots (xor 16, 32), per head
#pragma unroll
  for (int h = 0; h < G_; ++h) {
#pragma unroll
    for (int off = 16; off <= 32; off <<= 1) {
      const float mo = __shfl_xor(m[h], off);
      const float lo = __shfl_xor(l[h], off);
      float ao[8];
#pragma unroll
      for (int j = 0; j < 8; ++j) ao[j] = __shfl_xor(acc[h][j], off);
      const float mn = fmaxf(m[h], mo);
      const float se = exp2f(m[h] - mn);
      const float so_ = exp2f(mo - mn);
      l[h] = l[h] * se + lo * so_;
#pragma unroll
      for (int j = 0; j < 8; ++j) acc[h][j] = acc[h][j] * se + ao[j] * so_;
      m[h] = mn;
    }
  }

  if (tg == 0) {  // lanes 0-15 write dim chunks dl*4 and 64+dl*4
#pragma unroll
    for (int h = 0; h < G_; ++h) {
      float* wp = ws_o + ((size_t)gw * G_ + h) * D_;
      f32x4 a, c;
#pragma unroll
      for (int j = 0; j < 4; ++j) { a[j] = acc[h][j]; c[j] = acc[h][4 + j]; }
      *(f32x4*)(wp + dl * 4) = a;
      *(f32x4*)(wp + 64 + dl * 4) = c;
    }
  }
  if (lane == 0) {
#pragma unroll
    for (int h = 0; h < G_; ++h) {
      ws_m[gw * G_ + h] = m[h];  // log2-domain
      ws_l[gw * G_ + h] = l[h];
    }
  }
}

// ---------- kernel 2: LSE-weighted combine over R_*NR records ----------
__global__ __launch_bounds__(128) void fd_reduce(
    const float* __restrict__ ws_m, const float* __restrict__ ws_l,
    const float* __restrict__ ws_o, float* __restrict__ out) {
  const int row = blockIdx.x;  // (b*HK + hk)*G + g
  const int g = row % G_;
  const int hk = (row / G_) % HK_;
  const int b = row / (G_ * HK_);
  const int d = threadIdx.x;

  float mf = MNEG;
  for (int r = 0; r < R_; ++r)
    for (int s = 0; s < NR; ++s) {
      const int rec = s * 512 + (r * B_ + b) * HK_ + hk;
      mf = fmaxf(mf, ws_m[rec * G_ + g]);
    }
  float of = 0.f, lf = 0.f;
  for (int r = 0; r < R_; ++r)
    for (int s = 0; s < NR; ++s) {
      const int rec = s * 512 + (r * B_ + b) * HK_ + hk;
      const float wt = exp2f(ws_m[rec * G_ + g] - mf);  // empty -> 0
      of += wt * ws_o[((size_t)rec * G_ + g) * D_ + d];
      lf += wt * ws_l[rec * G_ + g];
    }
  out[(size_t)(b * HQ_ + hk * G_ + g) * D_ + d] = of / lf;
}

// ---------------- fallback: monolithic (tiny workspace) ----------------
__device__ __forceinline__ void load8u(const float* __restrict__ ubase,
                                       unsigned boff, float o[8]) {
  const f32x4* p = (const f32x4*)((const char*)ubase + boff);
  f32x4 a = p[0];
  f32x4 b = p[1];
#pragma unroll
  for (int j = 0; j < 4; ++j) { o[j] = a[j]; o[4 + j] = b[j]; }
}

__global__ __launch_bounds__(256) void fd_mono(
    const float* __restrict__ q, const float* __restrict__ kc,
    const float* __restrict__ vc, const int* __restrict__ lens,
    const int* __restrict__ bt, float* __restrict__ out) {
  const int hk = blockIdx.x % HK_;
  const int b = blockIdx.x / HK_;
  const int lane = threadIdx.x & 63;
  const int g = threadIdx.x >> 6;
  const int tg = lane >> 4;
  const int ds = (lane & 15) * 8;
  const unsigned dsb = ds * 4u;

  float qf[8];
  load8u(q + (size_t)(b * HQ_ + hk * G_ + g) * D_ + ds, 0u, qf);
#pragma unroll
  for (int j = 0; j < 8; ++j) qf[j] *= SC2;

  float m = MNEG, l = 0.f, acc[8];
#pragma unroll
  for (int j = 0; j < 8; ++j) acc[j] = 0.f;

  for (int r = 0; r < R_; ++r) {
    int kvlen = lens[r * B_ + b];
    if (kvlen < 0) kvlen = 0;
    if (kvlen > M_) kvlen = M_;
    const int* btrow = bt + (r * B_ + b) * M_;
    const float* kb = kc + (size_t)r * P_ * HKD + (size_t)hk * D_;
    const float* vb = vc + (size_t)r * P_ * HKD + (size_t)hk * D_;

#pragma unroll 1
    for (int t = 0; t < kvlen; t += 4) {
      const int ta = t + tg;
      const bool va = ta < kvlen;
      const unsigned oa = ((unsigned)clampP(btrow[va ? ta : 0]) << 12) + dsb;
      float ka[8], wa[8];
      load8u(kb, oa, ka);
      load8u(vb, oa, wa);

      float da = 0.f;
#pragma unroll
      for (int j = 0; j < 8; ++j) da += qf[j] * ka[j];
#pragma unroll
      for (int msk = 1; msk <= 8; msk <<= 1) da += __shfl_xor(da, msk);

      const float sa = va ? da : -INFINITY;
      const float mn = fmaxf(m, sa);
      const float sc = exp2f(m - mn);
      const float pa = exp2f(sa - mn);
      m = mn;
      l = l * sc + pa;
#pragma unroll
      for (int j = 0; j < 8; ++j) acc[j] = acc[j] * sc + pa * wa[j];
    }
  }

#pragma unroll
  for (int off = 16; off <= 32; off <<= 1) {
    const float mo = __shfl_xor(m, off);
    const float lo = __shfl_xor(l, off);
    float ao[8];
#pragma unroll
    for (int j = 0; j < 8; ++j) ao[j] = __shfl_xor(acc[j], off);
    const float mn = fmaxf(m, mo);
    const float se = exp2f(m - mn);
    const float so_ = exp2f(mo - mn);
    l = l * se + lo * so_;
#pragma unroll
    for (int j = 0; j < 8; ++j) acc[j] = acc[j] * se + ao[j] * so_;
    m = mn;
  }

  if (lane < 16) {
    float inv = (l > 0.f) ? 1.0f / l : 0.f;
#pragma unroll
    for (int j = 0; j < 8; ++j)
      out[(size_t)(b * HQ_ + hk * G_ + g) * D_ + ds + j] = acc[j] * inv;
  }
}

extern "C" void kernel_launch(void* const* d_in, const int* in_sizes, int n_in,
                              void* d_out, int out_size, void* d_ws,
                              size_t ws_size, hipStream_t stream) {
  const float* q = (const float*)d_in[0];
  const float* kc = (const float*)d_in[1];
  const float* vc = (const float*)d_in[2];
  const int* lens = (const int*)d_in[3];
  const int* bt = (const int*)d_in[4];
  float* out = (float*)d_out;

  const int nrec = NR * R_ * B_ * HK_;  // 4096 wave-records
  const size_t sz_pages = (size_t)R_ * B_ * PROW * 4;  // 540 KB
  const size_t sz_ml = (size_t)nrec * G_ * 4;          // 64 KB each
  const size_t sz_o = (size_t)nrec * G_ * D_ * 4;      // 8 MB
  const size_t need = sz_pages + 2 * sz_ml + sz_o;

  if (need <= ws_size) {
    char* p = (char*)d_ws;
    unsigned* ws_pages = (unsigned*)p;  p += sz_pages;
    float* ws_m = (float*)p;            p += sz_ml;
    float* ws_l = (float*)p;            p += sz_ml;
    float* ws_o = (float*)p;
    fd_compact<<<R_ * B_, 256, 0, stream>>>(lens, bt, ws_pages);
    fd_partial<<<nrec / WV, WV * 64, 0, stream>>>(q, kc, vc, lens, ws_pages,
                                                  ws_m, ws_l, ws_o);
    fd_reduce<<<B_ * HK_ * G_, 128, 0, stream>>>(ws_m, ws_l, ws_o, out);
  } else {
    fd_mono<<<B_ * HK_, 256, 0, stream>>>(q, kc, vc, lens, bt, out);
  }
}

// Round 21
// 124.084 us; speedup vs baseline: 1.0738x; 1.0662x over previous
//
#include <hip/hip_runtime.h>
#include <math.h>

// flash-decode, GQA paged KV. R=4, B=16, Hq=32, Hk=8 (G=4), D=128, P=8192,
// PAGE=1, M=2048. Storage (r7): q/k/v FLOAT32; lens/bt int32; out f32.
//
// Round 21: flat uniform work list over page-sorted chunks.
//  - fd_compact: per-(r,b) counting sort of block_table (r18, proven:
//    FETCH 262->119 MB via quantile-band L2/L3 dedup).
//  - fd_order: global list of FIXED 128-token chunks in quantile-major
//    order (qkey = lc*64/nchunks) -> ascending work index sweeps the same
//    page band across all (r,b) (r19's dedup mechanism) with EXACTLY
//    uniform per-wave work (the stuck 21-28% occupancy of r13-r20 was
//    kvlen-dependent per-block work variance).
//  - fd_partial: one independent wave per (chunk, hk); r13's proven body;
//    no barriers, no LDS; overshoot waves exit immediately.
//  - fd_reduce: walks each rb's records via rbstart prefix.

typedef float f32x4 __attribute__((ext_vector_type(4)));

#define R_ 4
#define B_ 16
#define HQ_ 32
#define HK_ 8
#define G_ 4
#define D_ 128
#define P_ 8192
#define M_ 2048
#define HKD (HK_ * D_)
#define NBK 256    // sort buckets (page >> 5)
#define PROW 2112  // padded sorted-row capacity
#define CHT 128    // tokens per work chunk
#define MAXCH 1024 // worst-case total chunks (64 rb x 16)
#define SC2 (0.08838834764831845f * 1.4426950408889634f)  // scale * log2(e)
#define MNEG (-1.0e30f)

__device__ __forceinline__ int clampP(int p) {
  return p < 0 ? 0 : (p >= P_ ? P_ - 1 : p);
}

__device__ __forceinline__ int clampKV(int kv) {
  return kv < 1 ? 1 : (kv > M_ ? M_ : kv);
}

// ---------- kernel 0: per-(r,b) counting sort + tail padding ----------
__global__ __launch_bounds__(256) void fd_compact(
    const int* __restrict__ lens, const int* __restrict__ bt,
    unsigned* __restrict__ ws_pages) {
  __shared__ int hist[NBK];
  __shared__ int cur[NBK];
  const int rb = blockIdx.x;
  const int tid = threadIdx.x;
  const int kvlen = clampKV(lens[rb]);
  const int* btrow = bt + rb * M_;

  for (int i = tid; i < NBK; i += 256) hist[i] = 0;
  __syncthreads();
  for (int t = tid; t < kvlen; t += 256)
    atomicAdd(&hist[clampP(btrow[t]) >> 5], 1);
  __syncthreads();
  if (tid == 0) {
    int pos = 0;
    for (int j = 0; j < NBK; ++j) {
      cur[j] = pos;
      pos += hist[j];
    }
  }
  __syncthreads();
  unsigned* prow = ws_pages + (size_t)rb * PROW;
  for (int t = tid; t < kvlen; t += 256) {
    const int p = clampP(btrow[t]);
    const int d = atomicAdd(&cur[p >> 5], 1);
    prow[d] = ((unsigned)p) << 12;  // byte offset of the page
  }
  __syncthreads();
  const unsigned last = prow[kvlen - 1];
  for (int i = kvlen + tid; i < PROW; i += 256) prow[i] = last;
}

// ---------- kernel 0.5: quantile-major work list (single block) ----------
// meta[64+rb] = rbstart (record-prefix), meta[128] = total chunks.
__global__ __launch_bounds__(256) void fd_order(const int* __restrict__ lens,
                                                int* __restrict__ meta,
                                                int* __restrict__ worklist) {
  __shared__ int nch[64], hist[64], cur[64];
  const int tid = threadIdx.x;
  if (tid < 64) {
    nch[tid] = (clampKV(lens[tid]) + CHT - 1) / CHT;
    hist[tid] = 0;
  }
  __syncthreads();
  for (int idx = tid; idx < 64 * 16; idx += 256) {
    const int rb = idx & 63, lc = idx >> 6;
    if (lc < nch[rb]) atomicAdd(&hist[lc * 64 / nch[rb]], 1);
  }
  __syncthreads();
  if (tid == 0) {
    int pos = 0;
    for (int j = 0; j < 64; ++j) {
      cur[j] = pos;
      pos += hist[j];
    }
    meta[128] = pos;  // total chunks
    int ps = 0;
    for (int rb = 0; rb < 64; ++rb) {
      meta[64 + rb] = ps;
      ps += nch[rb];
    }
  }
  __syncthreads();
  for (int idx = tid; idx < 64 * 16; idx += 256) {
    const int rb = idx & 63, lc = idx >> 6;
    if (lc < nch[rb]) {
      const int p = atomicAdd(&cur[lc * 64 / nch[rb]], 1);
      worklist[p] = (rb << 5) | lc;
    }
  }
}

// ---------- kernel 1: one wave per (chunk, hk); r13 body ----------
__global__ __launch_bounds__(256) void fd_partial(
    const float* __restrict__ q, const float* __restrict__ kc,
    const float* __restrict__ vc, const int* __restrict__ lens,
    const unsigned* __restrict__ ws_pages, const int* __restrict__ meta,
    const int* __restrict__ worklist, float* __restrict__ ws_m,
    float* __restrict__ ws_l, float* __restrict__ ws_o) {
  const int lane = threadIdx.x & 63;
  const int gw = blockIdx.x * 4 + (threadIdx.x >> 6);
  const int total = meta[128];
  if (gw >= total * HK_) return;  // overshoot wave (worst-case grid)
  const int widx = gw >> 3;       // hk fastest: 8 neighbors share pages
  const int hk = gw & 7;
  const int ent = worklist[widx];
  const int rb = ent >> 5;
  const int lc = ent & 31;
  const int b = rb & (B_ - 1);
  const int r = rb >> 4;

  const int kvlen = clampKV(lens[rb]);
  const int cs = lc * CHT;
  int ct = kvlen - cs;  // > 0 by construction
  if (ct > CHT) ct = CHT;
  const int rec = (meta[64 + rb] + lc) * HK_ + hk;

  const int tg = lane >> 4;        // slot 0..3: 4 contiguous tokens
  const int ds = (lane & 15) * 8;  // dim slice [ds, ds+8)
  const unsigned dsb = ds * 4u;

  // q fragments for all 4 heads, pre-scaled into log2 domain
  float qf[G_][8];
  {
    const float* qp = q + (size_t)(b * HQ_ + hk * G_) * D_ + ds;
#pragma unroll
    for (int h = 0; h < G_; ++h) {
      const f32x4* p = (const f32x4*)(qp + h * D_);
      f32x4 a = p[0], c = p[1];
#pragma unroll
      for (int j = 0; j < 4; ++j) {
        qf[h][j] = a[j] * SC2;
        qf[h][4 + j] = c[j] * SC2;
      }
    }
  }

  const unsigned* plist = ws_pages + (size_t)rb * PROW + cs;
  const float* kb = kc + (size_t)r * P_ * HKD + (size_t)hk * D_;
  const float* vb = vc + (size_t)r * P_ * HKD + (size_t)hk * D_;

  float m[G_], l[G_], acc[G_][8];
#pragma unroll
  for (int h = 0; h < G_; ++h) {
    m[h] = MNEG;
    l[h] = 0.f;
#pragma unroll
    for (int j = 0; j < 8; ++j) acc[h][j] = 0.f;
  }

  const int nIt = (ct + 15) >> 4;   // 16 tokens per iteration
  const int sbase = tg * 4;         // 4-aligned within padded row

  uint4 pgN = *(const uint4*)(plist + sbase);

#pragma unroll 1
  for (int i = 0; i < nIt; ++i) {
    const uint4 pg = pgN;
    if (i + 1 < nIt) pgN = *(const uint4*)(plist + sbase + (i + 1) * 16);
    const unsigned o0 = pg.x + dsb;
    const unsigned o1 = pg.y + dsb;
    const unsigned o2 = pg.z + dsb;
    const unsigned o3 = pg.w + dsb;

    float k0[8], k1[8], k2[8], k3[8], v0[8], v1[8], v2[8], v3[8];
    {
      const char* kcb = (const char*)kb;
      const char* vcb = (const char*)vb;
      const f32x4* p;
      p = (const f32x4*)(kcb + o0);
#pragma unroll
      for (int j = 0; j < 4; ++j) { k0[j] = p[0][j]; k0[4 + j] = p[1][j]; }
      p = (const f32x4*)(kcb + o1);
#pragma unroll
      for (int j = 0; j < 4; ++j) { k1[j] = p[0][j]; k1[4 + j] = p[1][j]; }
      p = (const f32x4*)(kcb + o2);
#pragma unroll
      for (int j = 0; j < 4; ++j) { k2[j] = p[0][j]; k2[4 + j] = p[1][j]; }
      p = (const f32x4*)(kcb + o3);
#pragma unroll
      for (int j = 0; j < 4; ++j) { k3[j] = p[0][j]; k3[4 + j] = p[1][j]; }
      p = (const f32x4*)(vcb + o0);
#pragma unroll
      for (int j = 0; j < 4; ++j) { v0[j] = p[0][j]; v0[4 + j] = p[1][j]; }
      p = (const f32x4*)(vcb + o1);
#pragma unroll
      for (int j = 0; j < 4; ++j) { v1[j] = p[0][j]; v1[4 + j] = p[1][j]; }
      p = (const f32x4*)(vcb + o2);
#pragma unroll
      for (int j = 0; j < 4; ++j) { v2[j] = p[0][j]; v2[4 + j] = p[1][j]; }
      p = (const f32x4*)(vcb + o3);
#pragma unroll
      for (int j = 0; j < 4; ++j) { v3[j] = p[0][j]; v3[4 + j] = p[1][j]; }
    }

    float d0[G_], d1[G_], d2[G_], d3[G_];
#pragma unroll
    for (int h = 0; h < G_; ++h) {
      float a0 = 0.f, a1 = 0.f, a2 = 0.f, a3 = 0.f;
#pragma unroll
      for (int j = 0; j < 8; ++j) {
        a0 += qf[h][j] * k0[j];
        a1 += qf[h][j] * k1[j];
        a2 += qf[h][j] * k2[j];
        a3 += qf[h][j] * k3[j];
      }
      d0[h] = a0; d1[h] = a1; d2[h] = a2; d3[h] = a3;
    }
#pragma unroll
    for (int msk = 1; msk <= 8; msk <<= 1) {
#pragma unroll
      for (int h = 0; h < G_; ++h) {
        d0[h] += __shfl_xor(d0[h], msk);
        d1[h] += __shfl_xor(d1[h], msk);
        d2[h] += __shfl_xor(d2[h], msk);
        d3[h] += __shfl_xor(d3[h], msk);
      }
    }

    const int tb = sbase + i * 16;  // index within the chunk
    const bool va0 = tb < ct;
    const bool va1 = tb + 1 < ct;
    const bool va2 = tb + 2 < ct;
    const bool va3 = tb + 3 < ct;
#pragma unroll
    for (int h = 0; h < G_; ++h) {
      const float s0 = va0 ? d0[h] : -INFINITY;
      const float s1 = va1 ? d1[h] : -INFINITY;
      const float s2 = va2 ? d2[h] : -INFINITY;
      const float s3 = va3 ? d3[h] : -INFINITY;
      const float mt = fmaxf(fmaxf(s0, s1), fmaxf(s2, s3));
      const float mn = fmaxf(m[h], mt);   // finite always (>= MNEG)
      const float sc = exp2f(m[h] - mn);  // branchless, no NaN
      const float p0 = exp2f(s0 - mn);    // -inf -> 0
      const float p1 = exp2f(s1 - mn);
      const float p2 = exp2f(s2 - mn);
      const float p3 = exp2f(s3 - mn);
      m[h] = mn;
      l[h] = l[h] * sc + (p0 + p1) + (p2 + p3);
#pragma unroll
      for (int j = 0; j < 8; ++j)
        acc[h][j] = acc[h][j] * sc + p0 * v0[j] + p1 * v1[j] + p2 * v2[j] +
                    p3 * v3[j];
    }
  }

  // merge the 4 token slots (xor 16, 32), per head — branchless
#pragma unroll
  for (int h = 0; h < G_; ++h) {
#pragma unroll
    for (int off = 16; off <= 32; off <<= 1) {
      const float mo = __shfl_xor(m[h], off);
      const float lo = __shfl_xor(l[h], off);
      float ao[8];
#pragma unroll
      for (int j = 0; j < 8; ++j) ao[j] = __shfl_xor(acc[h][j], off);
      const float mn = fmaxf(m[h], mo);
      const float se = exp2f(m[h] - mn);
      const float so_ = exp2f(mo - mn);
      l[h] = l[h] * se + lo * so_;
#pragma unroll
      for (int j = 0; j < 8; ++j) acc[h][j] = acc[h][j] * se + ao[j] * so_;
      m[h] = mn;
    }
  }

  if (lane < 16) {  // lanes 0-15 hold the full 128 dims after the merge
#pragma unroll
    for (int h = 0; h < G_; ++h) {
      float* wp = ws_o + ((size_t)rec * G_ + h) * D_ + ds;
#pragma unroll
      for (int j = 0; j < 8; ++j) wp[j] = acc[h][j];
    }
  }
  if (lane == 0) {
#pragma unroll
    for (int h = 0; h < G_; ++h) {
      ws_m[rec * G_ + h] = m[h];  // log2-domain
      ws_l[rec * G_ + h] = l[h];
    }
  }
}

// ---------- kernel 2: LSE-weighted combine over each rb's chunks ----------
__global__ __launch_bounds__(128) void fd_reduce(
    const int* __restrict__ lens, const int* __restrict__ meta,
    const float* __restrict__ ws_m, const float* __restrict__ ws_l,
    const float* __restrict__ ws_o, float* __restrict__ out) {
  const int row = blockIdx.x;  // (b*HK + hk)*G + g
  const int g = row % G_;
  const int hk = (row / G_) % HK_;
  const int b = row / (G_ * HK_);
  const int d = threadIdx.x;

  float mf = MNEG;
  for (int r = 0; r < R_; ++r) {
    const int rb = r * B_ + b;
    const int n = (clampKV(lens[rb]) + CHT - 1) / CHT;
    const int base = meta[64 + rb];
    for (int lc = 0; lc < n; ++lc) {
      const int rec = (base + lc) * HK_ + hk;
      mf = fmaxf(mf, ws_m[rec * G_ + g]);
    }
  }
  float of = 0.f, lf = 0.f;
  for (int r = 0; r < R_; ++r) {
    const int rb = r * B_ + b;
    const int n = (clampKV(lens[rb]) + CHT - 1) / CHT;
    const int base = meta[64 + rb];
    for (int lc = 0; lc < n; ++lc) {
      const int rec = (base + lc) * HK_ + hk;
      const float wt = exp2f(ws_m[rec * G_ + g] - mf);
      of += wt * ws_o[((size_t)rec * G_ + g) * D_ + d];
      lf += wt * ws_l[rec * G_ + g];
    }
  }
  out[(size_t)(b * HQ_ + hk * G_ + g) * D_ + d] = of / lf;
}

// ---------------- fallback: monolithic (tiny workspace) ----------------
__device__ __forceinline__ void load8u(const float* __restrict__ ubase,
                                       unsigned boff, float o[8]) {
  const f32x4* p = (const f32x4*)((const char*)ubase + boff);
  f32x4 a = p[0];
  f32x4 b = p[1];
#pragma unroll
  for (int j = 0; j < 4; ++j) { o[j] = a[j]; o[4 + j] = b[j]; }
}

__global__ __launch_bounds__(256) void fd_mono(
    const float* __restrict__ q, const float* __restrict__ kc,
    const float* __restrict__ vc, const int* __restrict__ lens,
    const int* __restrict__ bt, float* __restrict__ out) {
  const int hk = blockIdx.x % HK_;
  const int b = blockIdx.x / HK_;
  const int lane = threadIdx.x & 63;
  const int g = threadIdx.x >> 6;
  const int tg = lane >> 4;
  const int ds = (lane & 15) * 8;
  const unsigned dsb = ds * 4u;

  float qf[8];
  load8u(q + (size_t)(b * HQ_ + hk * G_ + g) * D_ + ds, 0u, qf);
#pragma unroll
  for (int j = 0; j < 8; ++j) qf[j] *= SC2;

  float m = MNEG, l = 0.f, acc[8];
#pragma unroll
  for (int j = 0; j < 8; ++j) acc[j] = 0.f;

  for (int r = 0; r < R_; ++r) {
    int kvlen = lens[r * B_ + b];
    if (kvlen < 0) kvlen = 0;
    if (kvlen > M_) kvlen = M_;
    const int* btrow = bt + (r * B_ + b) * M_;
    const float* kb = kc + (size_t)r * P_ * HKD + (size_t)hk * D_;
    const float* vb = vc + (size_t)r * P_ * HKD + (size_t)hk * D_;

#pragma unroll 1
    for (int t = 0; t < kvlen; t += 4) {
      const int ta = t + tg;
      const bool va = ta < kvlen;
      const unsigned oa = ((unsigned)clampP(btrow[va ? ta : 0]) << 12) + dsb;
      float ka[8], wa[8];
      load8u(kb, oa, ka);
      load8u(vb, oa, wa);

      float da = 0.f;
#pragma unroll
      for (int j = 0; j < 8; ++j) da += qf[j] * ka[j];
#pragma unroll
      for (int msk = 1; msk <= 8; msk <<= 1) da += __shfl_xor(da, msk);

      const float sa = va ? da : -INFINITY;
      const float mn = fmaxf(m, sa);
      const float sc = exp2f(m - mn);
      const float pa = exp2f(sa - mn);
      m = mn;
      l = l * sc + pa;
#pragma unroll
      for (int j = 0; j < 8; ++j) acc[j] = acc[j] * sc + pa * wa[j];
    }
  }

#pragma unroll
  for (int off = 16; off <= 32; off <<= 1) {
    const float mo = __shfl_xor(m, off);
    const float lo = __shfl_xor(l, off);
    float ao[8];
#pragma unroll
    for (int j = 0; j < 8; ++j) ao[j] = __shfl_xor(acc[j], off);
    const float mn = fmaxf(m, mo);
    const float se = exp2f(m - mn);
    const float so_ = exp2f(mo - mn);
    l = l * se + lo * so_;
#pragma unroll
    for (int j = 0; j < 8; ++j) acc[j] = acc[j] * se + ao[j] * so_;
    m = mn;
  }

  if (lane < 16) {
    float inv = (l > 0.f) ? 1.0f / l : 0.f;
#pragma unroll
    for (int j = 0; j < 8; ++j)
      out[(size_t)(b * HQ_ + hk * G_ + g) * D_ + ds + j] = acc[j] * inv;
  }
}

extern "C" void kernel_launch(void* const* d_in, const int* in_sizes, int n_in,
                              void* d_out, int out_size, void* d_ws,
                              size_t ws_size, hipStream_t stream) {
  const float* q = (const float*)d_in[0];
  const float* kc = (const float*)d_in[1];
  const float* vc = (const float*)d_in[2];
  const int* lens = (const int*)d_in[3];
  const int* bt = (const int*)d_in[4];
  float* out = (float*)d_out;

  const int maxrec = MAXCH * HK_;  // 8192 worst-case records
  const size_t sz_pages = (size_t)R_ * B_ * PROW * 4;  // 540 KB
  const size_t sz_meta = 1024;
  const size_t sz_wl = (size_t)MAXCH * 4;              // 4 KB
  const size_t sz_ml = (size_t)maxrec * G_ * 4;        // 128 KB each
  const size_t sz_o = (size_t)maxrec * G_ * D_ * 4;    // 16.8 MB
  const size_t need = sz_pages + sz_meta + sz_wl + 2 * sz_ml + sz_o;

  if (need <= ws_size) {
    char* p = (char*)d_ws;
    unsigned* ws_pages = (unsigned*)p;  p += sz_pages;
    int* meta = (int*)p;                p += sz_meta;
    int* worklist = (int*)p;            p += sz_wl;
    float* ws_m = (float*)p;            p += sz_ml;
    float* ws_l = (float*)p;            p += sz_ml;
    float* ws_o = (float*)p;
    fd_compact<<<R_ * B_, 256, 0, stream>>>(lens, bt, ws_pages);
    fd_order<<<1, 256, 0, stream>>>(lens, meta, worklist);
    fd_partial<<<maxrec / 4, 256, 0, stream>>>(q, kc, vc, lens, ws_pages,
                                               meta, worklist, ws_m, ws_l,
                                               ws_o);
    fd_reduce<<<B_ * HK_ * G_, 128, 0, stream>>>(lens, meta, ws_m, ws_l,
                                                 ws_o, out);
  } else {
    fd_mono<<<B_ * HK_, 256, 0, stream>>>(q, kc, vc, lens, bt, out);
  }
}